// Round 1
// baseline (281.226 us; speedup 1.0000x reference)
//
#include <hip/hip_runtime.h>
#include <math.h>

#define SD 768
#define SB 16
#define SM 8
#define SS 2048
#define TOK_ROW 2049

// ws layout (float offsets). Total 5,282,048 floats = 21.2 MB.
#define OFF_QS      0          // 8*768 + 16 (qs, qs1 @6144, qb @6152)
#define OFF_SCORES  6400       // 16*8*2048 = 262144 (reused in-place as attn)
#define OFF_PPOOL   268544     // 32*16*3*768 = 1179648
#define OFF_PTRAD   1448192    // 16*2304 = 36864
#define OFF_PMERG   1485056    // 32*16*8*768 = 3145728
#define OFF_PLEARN  4630784    // 16*6912 = 110592
#define OFF_P1A     4741376    // 9*12288
#define OFF_P1B     4851968    // 27*12288
#define OFF_HA      5183744    // 12288
#define OFF_HB      5196032    // 12288
#define OFF_P2A     5208320    // 3*12288
#define OFF_P2B     5245184    // 3*12288

__device__ __forceinline__ int clen(int v) { return v < 1 ? 1 : (v > SS ? SS : v); }

// ---------------- K0: qs = q*scale, qs1[m] = sum(qs), qb[m] = q.bias ----------
__global__ void k0_qs(const float* __restrict__ q, const float* __restrict__ lns,
                      const float* __restrict__ lnb, float* __restrict__ qsbuf) {
  int m = blockIdx.x, tid = threadIdx.x;
  float s1 = 0.f, sb = 0.f;
  #pragma unroll
  for (int g = 0; g < 3; ++g) {
    int d = g * 256 + tid;
    float qv = q[m * SD + d];
    float qsv = qv * lns[d];
    qsbuf[m * SD + d] = qsv;
    s1 += qsv;
    sb += qv * lnb[d];
  }
  __shared__ float rb1[4], rb2[4];
  #pragma unroll
  for (int o = 32; o; o >>= 1) { s1 += __shfl_xor(s1, o, 64); sb += __shfl_xor(sb, o, 64); }
  if ((tid & 63) == 0) { rb1[tid >> 6] = s1; rb2[tid >> 6] = sb; }
  __syncthreads();
  if (tid == 0) {
    qsbuf[6144 + m] = rb1[0] + rb1[1] + rb1[2] + rb1[3];
    qsbuf[6152 + m] = rb2[0] + rb2[1] + rb2[2] + rb2[3];
  }
}

// ---------------- K1: fused pooling partials + LN-stats + scores --------------
// grid (32 s-chunks, 16 b), 256 thr = 4 waves; wave w owns rows [c0+16w, c0+16w+16)
__global__ __launch_bounds__(256, 2) void k1_main(
    const float* __restrict__ tokens, const int* __restrict__ lengths,
    const float* __restrict__ qsbuf, float* __restrict__ scores,
    float* __restrict__ ppool) {
  int c = blockIdx.x, b = blockIdx.y;
  int len = clen(lengths[b]);
  int c0 = c * 64;
  if (c0 >= len) return;
  int tid = threadIdx.x, w = tid >> 6, lane = tid & 63;

  float4 qr[8][3];
  #pragma unroll
  for (int m = 0; m < 8; ++m)
    #pragma unroll
    for (int g = 0; g < 3; ++g)
      qr[m][g] = *reinterpret_cast<const float4*>(qsbuf + m * SD + g * 256 + lane * 4);
  float qs1r[8], qbr[8];
  #pragma unroll
  for (int m = 0; m < 8; ++m) { qs1r[m] = qsbuf[6144 + m]; qbr[m] = qsbuf[6152 + m]; }

  float psum[12], pmax[12], pmin[12];
  #pragma unroll
  for (int j = 0; j < 12; ++j) {
    psum[j] = 0.f; pmax[j] = -__builtin_inff(); pmin[j] = __builtin_inff();
  }

  __shared__ float pool_lds[4][3][SD];

  int srow = c0 + w * 16;
  for (int i = 0; i < 16; ++i) {
    int s = srow + i;
    if (s >= len) break;  // wave-uniform
    const float* xp = tokens + ((size_t)b * TOK_ROW + 1 + s) * SD;
    float4 x0 = *reinterpret_cast<const float4*>(xp + lane * 4);
    float4 x1 = *reinterpret_cast<const float4*>(xp + 256 + lane * 4);
    float4 x2 = *reinterpret_cast<const float4*>(xp + 512 + lane * 4);
    float xv[12] = {x0.x, x0.y, x0.z, x0.w, x1.x, x1.y, x1.z, x1.w,
                    x2.x, x2.y, x2.z, x2.w};
    float s1 = 0.f, s2 = 0.f;
    #pragma unroll
    for (int j = 0; j < 12; ++j) {
      float v = xv[j];
      psum[j] += v;
      pmax[j] = fmaxf(pmax[j], v);
      pmin[j] = fminf(pmin[j], v);
      s1 += v;
      s2 += v * v;
    }
    #pragma unroll
    for (int o = 32; o; o >>= 1) { s1 += __shfl_xor(s1, o, 64); s2 += __shfl_xor(s2, o, 64); }
    float mu = s1 * (1.f / 768.f);
    float var = s2 * (1.f / 768.f) - mu * mu;
    float rstd = rsqrtf(var + 1e-5f);
    float dot[8];
    #pragma unroll
    for (int m = 0; m < 8; ++m) {
      float4 a0 = qr[m][0], a1 = qr[m][1], a2 = qr[m][2];
      dot[m] = a0.x * xv[0] + a0.y * xv[1] + a0.z * xv[2] + a0.w * xv[3]
             + a1.x * xv[4] + a1.y * xv[5] + a1.z * xv[6] + a1.w * xv[7]
             + a2.x * xv[8] + a2.y * xv[9] + a2.z * xv[10] + a2.w * xv[11];
      #pragma unroll
      for (int o = 32; o; o >>= 1) dot[m] += __shfl_xor(dot[m], o, 64);
    }
    float sc[8];
    #pragma unroll
    for (int m = 0; m < 8; ++m)
      sc[m] = (rstd * dot[m] - rstd * mu * qs1r[m] + qbr[m]) * 0.03608439182435161f;
    float v = sc[0];
    v = (lane == 1) ? sc[1] : v;
    v = (lane == 2) ? sc[2] : v;
    v = (lane == 3) ? sc[3] : v;
    v = (lane == 4) ? sc[4] : v;
    v = (lane == 5) ? sc[5] : v;
    v = (lane == 6) ? sc[6] : v;
    v = (lane == 7) ? sc[7] : v;
    if (lane < 8) scores[((size_t)b * 8 + lane) * SS + s] = v;
  }

  #pragma unroll
  for (int g = 0; g < 3; ++g)
    #pragma unroll
    for (int u = 0; u < 4; ++u) {
      int d = g * 256 + lane * 4 + u;
      pool_lds[w][0][d] = psum[g * 4 + u];
      pool_lds[w][1][d] = pmax[g * 4 + u];
      pool_lds[w][2][d] = pmin[g * 4 + u];
    }
  __syncthreads();
  for (int j = tid; j < 2304; j += 256) {
    int stat = j / SD, d = j - stat * SD;
    float v0 = pool_lds[0][stat][d], v1 = pool_lds[1][stat][d];
    float v2 = pool_lds[2][stat][d], v3 = pool_lds[3][stat][d];
    float r;
    if (stat == 0) r = v0 + v1 + v2 + v3;
    else if (stat == 1) r = fmaxf(fmaxf(v0, v1), fmaxf(v2, v3));
    else r = fminf(fminf(v0, v1), fminf(v2, v3));
    ppool[((size_t)(c * SB + b) * 3 + stat) * SD + d] = r;
  }
}

// ---------------- K2: reduce pool partials over chunks -> pooled_trad ---------
__global__ void k2_poolreduce(const float* __restrict__ ppool,
                              const int* __restrict__ lengths,
                              float* __restrict__ ptrad) {
  int b = blockIdx.y;
  int j = blockIdx.x * 256 + threadIdx.x;  // < 2304
  int len = clen(lengths[b]);
  int nv = (len + 63) >> 6;
  int stat = j / SD;
  float acc = (stat == 0) ? 0.f : (stat == 1 ? -__builtin_inff() : __builtin_inff());
  for (int cc = 0; cc < nv; ++cc) {
    float v = ppool[(size_t)(cc * SB + b) * 2304 + j];
    if (stat == 0) acc += v;
    else if (stat == 1) acc = fmaxf(acc, v);
    else acc = fminf(acc, v);
  }
  if (stat == 0) acc /= (float)len;
  ptrad[b * 2304 + j] = acc;
}

// ---------------- K3: masked softmax over s, in-place -------------------------
__global__ void k3_softmax(float* __restrict__ scores, const int* __restrict__ lengths) {
  int bm = blockIdx.x;
  int len = clen(lengths[bm >> 3]);
  float* sc = scores + (size_t)bm * SS;
  int tid = threadIdx.x;
  __shared__ float rb[4];
  float v[8];
  int cnt = 0;
  float mx = -__builtin_inff();
  for (int s = tid; s < len; s += 256) { float x = sc[s]; v[cnt++] = x; mx = fmaxf(mx, x); }
  #pragma unroll
  for (int o = 32; o; o >>= 1) mx = fmaxf(mx, __shfl_xor(mx, o, 64));
  if ((tid & 63) == 0) rb[tid >> 6] = mx;
  __syncthreads();
  mx = fmaxf(fmaxf(rb[0], rb[1]), fmaxf(rb[2], rb[3]));
  __syncthreads();
  float sum = 0.f;
  for (int i = 0; i < cnt; ++i) { v[i] = expf(v[i] - mx); sum += v[i]; }
  #pragma unroll
  for (int o = 32; o; o >>= 1) sum += __shfl_xor(sum, o, 64);
  if ((tid & 63) == 0) rb[tid >> 6] = sum;
  __syncthreads();
  sum = rb[0] + rb[1] + rb[2] + rb[3];
  float inv = 1.f / sum;
  cnt = 0;
  for (int s = tid; s < len; s += 256) sc[s] = v[cnt++] * inv;
}

// ---------------- K4: merged partials = attn @ x over s-chunks ----------------
// grid (32 chunks, 16 b); wave w owns d-range [192w, 192w+192)
__global__ __launch_bounds__(256) void k4_merge(
    const float* __restrict__ attn, const float* __restrict__ tokens,
    const int* __restrict__ lengths, float* __restrict__ pmerg) {
  int c = blockIdx.x, b = blockIdx.y;
  int len = clen(lengths[b]);
  int c0 = c * 64;
  if (c0 >= len) return;
  __shared__ float at[8][64];
  int tid = threadIdx.x;
  for (int i = tid; i < 512; i += 256) {
    int m = i >> 6, sl = i & 63;
    int s = c0 + sl;
    at[m][sl] = (s < len) ? attn[((size_t)b * 8 + m) * SS + s] : 0.f;
  }
  __syncthreads();
  int w = tid >> 6, lane = tid & 63;
  int d0 = w * 192 + lane;
  float acc[8][3];
  #pragma unroll
  for (int m = 0; m < 8; ++m)
    #pragma unroll
    for (int g = 0; g < 3; ++g) acc[m][g] = 0.f;
  int smax = len - c0; if (smax > 64) smax = 64;
  const float* xbase = tokens + ((size_t)b * TOK_ROW + 1 + c0) * SD + d0;
  for (int sl = 0; sl < smax; ++sl) {
    const float* xp = xbase + (size_t)sl * SD;
    float xa = xp[0], xb = xp[64], xc = xp[128];
    #pragma unroll
    for (int m = 0; m < 8; ++m) {
      float a = at[m][sl];
      acc[m][0] += a * xa; acc[m][1] += a * xb; acc[m][2] += a * xc;
    }
  }
  #pragma unroll
  for (int m = 0; m < 8; ++m)
    #pragma unroll
    for (int g = 0; g < 3; ++g)
      pmerg[(size_t)(c * SB + b) * 6144 + m * SD + d0 + g * 64] = acc[m][g];
}

// ---------------- K5: reduce merged partials + clf -> pooled_learn ------------
__global__ void k5_plearn(const float* __restrict__ pmerg, const float* __restrict__ tokens,
                          const int* __restrict__ lengths, float* __restrict__ plearn) {
  int j = blockIdx.x * 256 + threadIdx.x;  // < 110592
  int b = j / 6912, col = j - b * 6912;
  float r;
  if (col < 6144) {
    int len = clen(lengths[b]);
    int nv = (len + 63) >> 6;
    r = 0.f;
    for (int cc = 0; cc < nv; ++cc) r += pmerg[(size_t)(cc * SB + b) * 6144 + col];
  } else {
    r = tokens[(size_t)b * TOK_ROW * SD + (col - 6144)];
  }
  plearn[j] = r;
}

// ---------------- split-K GEMM partial: (16 x K) @ (K x 768) ------------------
// grid (12 n-tiles, ktA+ktB); k-tile = 256. X staged transposed in LDS.
__global__ __launch_bounds__(256) void gemm_partial(
    const float* __restrict__ XA, const float* __restrict__ WA, int ktA, float* __restrict__ PA,
    const float* __restrict__ XB, const float* __restrict__ WB, float* __restrict__ PB) {
  int nt = blockIdx.x, ky = blockIdx.y;
  const float *X, *W; float* P; int kt, ktN;
  if (ky < ktA) { X = XA; W = WA; P = PA; kt = ky; ktN = ktA; }
  else { X = XB; W = WB; P = PB; kt = ky - ktA; ktN = gridDim.y - ktA; }
  int K = ktN * 256;
  int k0 = kt * 256;
  __shared__ __align__(16) float xt[256 * 20];
  __shared__ float red[4][64][17];
  int tid = threadIdx.x;
  #pragma unroll
  for (int b2 = 0; b2 < 16; ++b2) xt[tid * 20 + b2] = X[b2 * K + k0 + tid];
  __syncthreads();
  int w = tid >> 6, lane = tid & 63;
  int n = nt * 64 + lane;
  float acc[16];
  #pragma unroll
  for (int b2 = 0; b2 < 16; ++b2) acc[b2] = 0.f;
  const float* Wp = W + (size_t)k0 * SD + n;
  #pragma unroll 4
  for (int kj = 0; kj < 64; ++kj) {
    int k = w + kj * 4;
    float wv = Wp[(size_t)k * SD];
    const float4* xr = reinterpret_cast<const float4*>(xt + k * 20);
    float4 a0 = xr[0], a1 = xr[1], a2 = xr[2], a3 = xr[3];
    acc[0] += wv * a0.x; acc[1] += wv * a0.y; acc[2] += wv * a0.z; acc[3] += wv * a0.w;
    acc[4] += wv * a1.x; acc[5] += wv * a1.y; acc[6] += wv * a1.z; acc[7] += wv * a1.w;
    acc[8] += wv * a2.x; acc[9] += wv * a2.y; acc[10] += wv * a2.z; acc[11] += wv * a2.w;
    acc[12] += wv * a3.x; acc[13] += wv * a3.y; acc[14] += wv * a3.z; acc[15] += wv * a3.w;
  }
  #pragma unroll
  for (int b2 = 0; b2 < 16; ++b2) red[w][lane][b2] = acc[b2];
  __syncthreads();
  for (int i = tid; i < 1024; i += 256) {
    int nn = i & 63, b2 = i >> 6;
    float r = red[0][nn][b2] + red[1][nn][b2] + red[2][nn][b2] + red[3][nn][b2];
    P[(size_t)(kt * 16 + b2) * SD + nt * 64 + nn] = r;
  }
}

// ---------------- reduce + bias + exact GELU ---------------------------------
__global__ void gelu_reduce(const float* __restrict__ PA, const float* __restrict__ b1a,
                            float* __restrict__ HA, const float* __restrict__ PB,
                            const float* __restrict__ b1b, float* __restrict__ HB,
                            int npA, int npB) {
  int y = blockIdx.y;
  const float* P = y ? PB : PA;
  const float* bias = y ? b1b : b1a;
  float* H = y ? HB : HA;
  int np = y ? npB : npA;
  int j = blockIdx.x * 256 + threadIdx.x;  // < 12288
  float r = 0.f;
  for (int kt = 0; kt < np; ++kt) r += P[kt * 12288 + j];
  r += bias[j % SD];
  H[j] = r * 0.5f * (1.f + erff(r * 0.70710678118654752f));
}

// ---------------- final: reduce + bias -> d_out ------------------------------
__global__ void final_reduce(const float* __restrict__ P2A, const float* __restrict__ b2a,
                             const float* __restrict__ P2B, const float* __restrict__ b2b,
                             float* __restrict__ out) {
  int y = blockIdx.y;
  const float* P = y ? P2B : P2A;
  const float* bias = y ? b2b : b2a;
  int j = blockIdx.x * 256 + threadIdx.x;  // < 12288
  float r = P[j] + P[12288 + j] + P[24576 + j] + bias[j % SD];
  int b = j / SD, nn = j - b * SD;
  out[b * 1536 + y * SD + nn] = r;
}

extern "C" void kernel_launch(void* const* d_in, const int* in_sizes, int n_in,
                              void* d_out, int out_size, void* d_ws, size_t ws_size,
                              hipStream_t stream) {
  const float* tokens = (const float*)d_in[0];
  const int* lengths  = (const int*)d_in[1];
  const float* q      = (const float*)d_in[2];
  const float* lns    = (const float*)d_in[3];
  const float* lnb    = (const float*)d_in[4];
  const float* w1a    = (const float*)d_in[5];
  const float* b1a    = (const float*)d_in[6];
  const float* w2a    = (const float*)d_in[7];
  const float* b2a    = (const float*)d_in[8];
  const float* w1b    = (const float*)d_in[9];
  const float* b1b    = (const float*)d_in[10];
  const float* w2b    = (const float*)d_in[11];
  const float* b2b    = (const float*)d_in[12];
  float* ws  = (float*)d_ws;
  float* out = (float*)d_out;

  float* qsbuf  = ws + OFF_QS;
  float* scores = ws + OFF_SCORES;
  float* ppool  = ws + OFF_PPOOL;
  float* ptrad  = ws + OFF_PTRAD;
  float* pmerg  = ws + OFF_PMERG;
  float* plearn = ws + OFF_PLEARN;
  float* p1a    = ws + OFF_P1A;
  float* p1b    = ws + OFF_P1B;
  float* ha     = ws + OFF_HA;
  float* hb     = ws + OFF_HB;
  float* p2a    = ws + OFF_P2A;
  float* p2b    = ws + OFF_P2B;

  k0_qs<<<8, 256, 0, stream>>>(q, lns, lnb, qsbuf);
  k1_main<<<dim3(32, 16), 256, 0, stream>>>(tokens, lengths, qsbuf, scores, ppool);
  k2_poolreduce<<<dim3(9, 16), 256, 0, stream>>>(ppool, lengths, ptrad);
  k3_softmax<<<128, 256, 0, stream>>>(scores, lengths);
  k4_merge<<<dim3(32, 16), 256, 0, stream>>>(scores, tokens, lengths, pmerg);
  k5_plearn<<<432, 256, 0, stream>>>(pmerg, tokens, lengths, plearn);
  gemm_partial<<<dim3(12, 36), 256, 0, stream>>>(ptrad, w1a, 9, p1a, plearn, w1b, p1b);
  gelu_reduce<<<dim3(48, 2), 256, 0, stream>>>(p1a, b1a, ha, p1b, b1b, hb, 9, 27);
  gemm_partial<<<dim3(12, 6), 256, 0, stream>>>(ha, w2a, 3, p2a, hb, w2b, p2b);
  final_reduce<<<dim3(48, 2), 256, 0, stream>>>(p2a, b2a, p2b, b2b, out);
}